// Round 1
// baseline (478.753 us; speedup 1.0000x reference)
//
#include <hip/hip_runtime.h>

// Problem constants (from reference): N=50000 nodes, E=800000 edges, D=128, L=2.
// Inputs: x fp32 [N,128], edge_index int32 [2,E] (src row 0, dst row 1),
//         W fp32 [L,128,128], b fp32 [L,128]. Output fp32 [N,128].

#define D 128
#define D4 32   // D/4 float4s per row
#define D2 64   // D/2 float2s per row

// ---------------- setup kernels ----------------

__global__ void init_kernel(int* degInt, int* cursor, int n) {
    int i = blockIdx.x * blockDim.x + threadIdx.x;
    if (i < n) { degInt[i] = 1; cursor[i] = 0; }  // deg starts at 1 (self-loop)
}

__global__ void count_kernel(const int* __restrict__ dst, int* degInt, int e) {
    int i = blockIdx.x * blockDim.x + threadIdx.x;
    if (i < e) atomicAdd(&degInt[dst[i]], 1);
}

__global__ void dinv_kernel(const int* __restrict__ degInt, float* __restrict__ dinv, int n) {
    int i = blockIdx.x * blockDim.x + threadIdx.x;
    if (i < n) dinv[i] = rsqrtf((float)degInt[i]);
}

// Single-block exclusive scan of (degInt[i]-1) over n elements -> row_ptr[0..n]
__global__ __launch_bounds__(1024) void scan_kernel(const int* __restrict__ degInt,
                                                    int* __restrict__ row_ptr, int n) {
    __shared__ int sums[1024];
    int tid = threadIdx.x;
    int chunk = (n + 1023) / 1024;
    int start = tid * chunk;
    int end = start + chunk; if (end > n) end = n; if (start > n) start = n;
    int s = 0;
    for (int i = start; i < end; ++i) s += degInt[i] - 1;
    sums[tid] = s;
    __syncthreads();
    // Hillis-Steele inclusive scan
    for (int off = 1; off < 1024; off <<= 1) {
        int v = 0;
        if (tid >= off) v = sums[tid - off];
        __syncthreads();
        if (tid >= off) sums[tid] += v;
        __syncthreads();
    }
    int run = sums[tid] - s;  // exclusive prefix for this chunk
    for (int i = start; i < end; ++i) {
        row_ptr[i] = run;
        run += degInt[i] - 1;
    }
    if (tid == 1023) row_ptr[n] = sums[1023];  // total = E
}

__global__ void fill_kernel(const int* __restrict__ src, const int* __restrict__ dst,
                            const int* __restrict__ row_ptr, int* cursor,
                            const float* __restrict__ dinv,
                            int* __restrict__ col, float* __restrict__ coefv, int e) {
    int i = blockIdx.x * blockDim.x + threadIdx.x;
    if (i < e) {
        int d = dst[i];
        int s = src[i];
        int pos = row_ptr[d] + atomicAdd(&cursor[d], 1);
        col[pos] = s;
        coefv[pos] = dinv[s] * dinv[d];
    }
}

// ---------------- GEMM: H[n x 128] = X[n x 128] @ W[128 x 128] ----------------
// 256 threads, 64-row tile. X tile staged in LDS (32KB). W from global (L2-hot).
// Thread (ty,tx): ty in [0,8) -> rows ty*8..ty*8+7; tx in [0,32) -> cols 4tx..4tx+3.

__global__ __launch_bounds__(256) void gemm_kernel(const float* __restrict__ X,
                                                   const float* __restrict__ W,
                                                   float* __restrict__ H, int n) {
    __shared__ float xs[64 * 128];  // 32 KB
    const int row0 = blockIdx.x * 64;
    const int tid = threadIdx.x;

    const float4* X4 = (const float4*)X;
    float4* xs4 = (float4*)xs;
#pragma unroll
    for (int q = 0; q < 8; ++q) {
        int idx = tid + q * 256;          // 0..2047
        int r = idx >> 5;                 // tile row
        int c4 = idx & 31;                // float4 col
        int gr = row0 + r; if (gr >= n) gr = n - 1;
        xs4[idx] = X4[gr * D4 + c4];
    }
    __syncthreads();

    const int tx = tid & 31;
    const int ty = tid >> 5;
    float4 acc[8];
#pragma unroll
    for (int i = 0; i < 8; ++i) acc[i] = make_float4(0.f, 0.f, 0.f, 0.f);

    const float4* W4 = (const float4*)W;
    for (int k4 = 0; k4 < 32; ++k4) {
        float4 a[8];
#pragma unroll
        for (int i = 0; i < 8; ++i) a[i] = xs4[(ty * 8 + i) * 32 + k4];
#pragma unroll
        for (int kk = 0; kk < 4; ++kk) {
            float4 w = W4[(k4 * 4 + kk) * 32 + tx];
#pragma unroll
            for (int i = 0; i < 8; ++i) {
                float av = (kk == 0) ? a[i].x : (kk == 1) ? a[i].y : (kk == 2) ? a[i].z : a[i].w;
                acc[i].x = fmaf(av, w.x, acc[i].x);
                acc[i].y = fmaf(av, w.y, acc[i].y);
                acc[i].z = fmaf(av, w.z, acc[i].z);
                acc[i].w = fmaf(av, w.w, acc[i].w);
            }
        }
    }

    float4* H4 = (float4*)H;
#pragma unroll
    for (int i = 0; i < 8; ++i) {
        int r = row0 + ty * 8 + i;
        if (r < n) H4[r * D4 + tx] = acc[i];
    }
}

// ---------------- Aggregation: Y[v] = relu( sum_{e->v} coef*H[src] + dinv[v]^2*H[v] + b )
// One wave (64 lanes) per node; lane owns a float2 of the feature row.

__global__ __launch_bounds__(256) void agg_kernel(const float* __restrict__ H,
                                                  const int* __restrict__ col,
                                                  const float* __restrict__ coefv,
                                                  const int* __restrict__ row_ptr,
                                                  const float* __restrict__ dinv,
                                                  const float* __restrict__ bias,
                                                  float* __restrict__ Y, int n) {
    int wave = threadIdx.x >> 6;
    int lane = threadIdx.x & 63;
    int v = blockIdx.x * 4 + wave;
    if (v >= n) return;

    const float2* H2 = (const float2*)H;
    float di = dinv[v];
    float selfc = di * di;
    float2 hv = H2[v * D2 + lane];
    float ax = hv.x * selfc;
    float ay = hv.y * selfc;

    int e0 = row_ptr[v];
    int e1 = row_ptr[v + 1];
    for (int e = e0; e < e1; ++e) {
        int s = col[e];
        float c = coefv[e];
        float2 hs = H2[s * D2 + lane];
        ax = fmaf(hs.x, c, ax);
        ay = fmaf(hs.y, c, ay);
    }
    float2 bv = ((const float2*)bias)[lane];
    float ox = ax + bv.x;
    float oy = ay + bv.y;
    ox = ox > 0.f ? ox : 0.f;
    oy = oy > 0.f ? oy : 0.f;
    ((float2*)Y)[v * D2 + lane] = make_float2(ox, oy);
}

// ---------------- launch ----------------

extern "C" void kernel_launch(void* const* d_in, const int* in_sizes, int n_in,
                              void* d_out, int out_size, void* d_ws, size_t ws_size,
                              hipStream_t stream) {
    const float* x = (const float*)d_in[0];
    const int* ei = (const int*)d_in[1];
    const float* W = (const float*)d_in[2];
    const float* b = (const float*)d_in[3];
    float* out = (float*)d_out;

    const int N = in_sizes[0] / D;       // 50000
    const int E = in_sizes[1] / 2;       // 800000
    const int L = in_sizes[2] / (D * D); // 2

    const int* src = ei;
    const int* dst = ei + E;

    // Workspace layout (element offsets, 4-byte units; regions 16B-aligned)
    int* wsi = (int*)d_ws;
    float* wsf = (float*)d_ws;
    const size_t o_deg    = 0;               // N ints
    const size_t o_cursor = o_deg + 50000;   // N ints
    const size_t o_dinv   = o_cursor + 50000;// N floats
    const size_t o_rp     = o_dinv + 50000;  // N+1 ints (padded to 50016)
    const size_t o_col    = o_rp + 50016;    // E ints
    const size_t o_coef   = o_col + 800000;  // E floats
    const size_t o_h      = o_coef + 800000; // N*D floats
    const size_t o_y1     = o_h + 6400000;   // N*D floats

    int* degInt  = wsi + o_deg;
    int* cursor  = wsi + o_cursor;
    float* dinv  = wsf + o_dinv;
    int* row_ptr = wsi + o_rp;
    int* col     = wsi + o_col;
    float* coefv = wsf + o_coef;
    float* h     = wsf + o_h;
    float* y1    = wsf + o_y1;

    const int nb_n = (N + 255) / 256;  // 196
    const int nb_e = (E + 255) / 256;  // 3125

    init_kernel<<<nb_n, 256, 0, stream>>>(degInt, cursor, N);
    count_kernel<<<nb_e, 256, 0, stream>>>(dst, degInt, E);
    dinv_kernel<<<nb_n, 256, 0, stream>>>(degInt, dinv, N);
    scan_kernel<<<1, 1024, 0, stream>>>(degInt, row_ptr, N);
    fill_kernel<<<nb_e, 256, 0, stream>>>(src, dst, row_ptr, cursor, dinv, col, coefv, E);

    const int nb_gemm = (N + 63) / 64;   // 782
    const int nb_agg  = (N + 3) / 4;     // 12500

    // Layer 0: h = x @ W0 ; y1 = agg(h) + b0, relu
    gemm_kernel<<<nb_gemm, 256, 0, stream>>>(x, W, h, N);
    agg_kernel<<<nb_agg, 256, 0, stream>>>(h, col, coefv, row_ptr, dinv, b, y1, N);
    // Layer 1: h = y1 @ W1 ; out = agg(h) + b1, relu
    gemm_kernel<<<nb_gemm, 256, 0, stream>>>(y1, W + D * D, h, N);
    agg_kernel<<<nb_agg, 256, 0, stream>>>(h, col, coefv, row_ptr, dinv, b + D, out, N);
}

// Round 2
// 462.954 us; speedup vs baseline: 1.0341x; 1.0341x over previous
//
#include <hip/hip_runtime.h>

// StaticGNN: 2-layer GCN. N=50000, E=800000, D=128, fp32.
// out = relu( D^{-1/2}(A+I)D^{-1/2} (X W_l) + b_l ), stacked twice.

#define D 128
#define D4 32   // D/4 float4s per row
#define D2 64   // D/2 float2s per row

// ---------------- setup kernels ----------------

// degInt starts zeroed (memset); counts in-edges only; deg = count + 1 (self-loop).
__global__ void count_kernel(const int* __restrict__ dst, int* degInt, int e) {
    int i = blockIdx.x * blockDim.x + threadIdx.x;
    if (i < e) atomicAdd(&degInt[dst[i]], 1);
}

// Single-block scan of edge counts -> row_ptr[0..n]; also dinv = rsqrt(count+1).
__global__ __launch_bounds__(1024) void scan_kernel(const int* __restrict__ degInt,
                                                    int* __restrict__ row_ptr,
                                                    float* __restrict__ dinv, int n) {
    __shared__ int sums[1024];
    int tid = threadIdx.x;
    int chunk = (n + 1023) / 1024;
    int start = tid * chunk;
    int end = start + chunk; if (end > n) end = n; if (start > n) start = n;
    int s = 0;
    for (int i = start; i < end; ++i) s += degInt[i];
    sums[tid] = s;
    __syncthreads();
    // Hillis-Steele inclusive scan over 1024 partials
    for (int off = 1; off < 1024; off <<= 1) {
        int v = 0;
        if (tid >= off) v = sums[tid - off];
        __syncthreads();
        if (tid >= off) sums[tid] += v;
        __syncthreads();
    }
    int run = sums[tid] - s;  // exclusive prefix for this chunk
    for (int i = start; i < end; ++i) {
        int c = degInt[i];
        row_ptr[i] = run;
        dinv[i] = rsqrtf((float)(c + 1));
        run += c;
    }
    if (tid == 1023) row_ptr[n] = sums[1023];  // total = E
}

__global__ void fill_kernel(const int* __restrict__ src, const int* __restrict__ dst,
                            const int* __restrict__ row_ptr, int* cursor,
                            const float* __restrict__ dinv,
                            int* __restrict__ col, float* __restrict__ coefv, int e) {
    int i = blockIdx.x * blockDim.x + threadIdx.x;
    if (i < e) {
        int d = dst[i];
        int s = src[i];
        int pos = row_ptr[d] + atomicAdd(&cursor[d], 1);
        col[pos] = s;
        coefv[pos] = dinv[s] * dinv[d];
    }
}

// ---------------- GEMM: H[n x 128] = X[n x 128] @ W[128 x 128] ----------------

__global__ __launch_bounds__(256) void gemm_kernel(const float* __restrict__ X,
                                                   const float* __restrict__ W,
                                                   float* __restrict__ H, int n) {
    __shared__ float xs[64 * 128];  // 32 KB
    const int row0 = blockIdx.x * 64;
    const int tid = threadIdx.x;

    const float4* X4 = (const float4*)X;
    float4* xs4 = (float4*)xs;
#pragma unroll
    for (int q = 0; q < 8; ++q) {
        int idx = tid + q * 256;          // 0..2047
        int r = idx >> 5;                 // tile row
        int c4 = idx & 31;                // float4 col
        int gr = row0 + r; if (gr >= n) gr = n - 1;
        xs4[idx] = X4[gr * D4 + c4];
    }
    __syncthreads();

    const int tx = tid & 31;
    const int ty = tid >> 5;
    float4 acc[8];
#pragma unroll
    for (int i = 0; i < 8; ++i) acc[i] = make_float4(0.f, 0.f, 0.f, 0.f);

    const float4* W4 = (const float4*)W;
    for (int k4 = 0; k4 < 32; ++k4) {
        float4 a[8];
#pragma unroll
        for (int i = 0; i < 8; ++i) a[i] = xs4[(ty * 8 + i) * 32 + k4];
#pragma unroll
        for (int kk = 0; kk < 4; ++kk) {
            float4 w = W4[(k4 * 4 + kk) * 32 + tx];
#pragma unroll
            for (int i = 0; i < 8; ++i) {
                float av = (kk == 0) ? a[i].x : (kk == 1) ? a[i].y : (kk == 2) ? a[i].z : a[i].w;
                acc[i].x = fmaf(av, w.x, acc[i].x);
                acc[i].y = fmaf(av, w.y, acc[i].y);
                acc[i].z = fmaf(av, w.z, acc[i].z);
                acc[i].w = fmaf(av, w.w, acc[i].w);
            }
        }
    }

    float4* H4 = (float4*)H;
#pragma unroll
    for (int i = 0; i < 8; ++i) {
        int r = row0 + ty * 8 + i;
        if (r < n) H4[r * D4 + tx] = acc[i];
    }
}

// ---------------- Aggregation ----------------
// Y[v] = relu( sum_{e->v} coef*H[src] + dinv[v]^2 * H[v] + b )
// One wave per node, lane owns a float2. Edge loop unrolled x8 so 8 gathers
// are in flight per wave (latency-bound fix: R1 had 1 dependent gather/iter).

__global__ __launch_bounds__(256) void agg_kernel(const float* __restrict__ H,
                                                  const int* __restrict__ col,
                                                  const float* __restrict__ coefv,
                                                  const int* __restrict__ row_ptr,
                                                  const float* __restrict__ dinv,
                                                  const float* __restrict__ bias,
                                                  float* __restrict__ Y, int n) {
    int wave = threadIdx.x >> 6;
    int lane = threadIdx.x & 63;
    int v = blockIdx.x * 4 + wave;
    if (v >= n) return;

    const float2* H2 = (const float2*)H;
    float di = dinv[v];
    float selfc = di * di;
    float2 hv = H2[(size_t)v * D2 + lane];
    float ax = hv.x * selfc;
    float ay = hv.y * selfc;

    int e0 = row_ptr[v];
    int e1 = row_ptr[v + 1];
    int e = e0;
    for (; e + 8 <= e1; e += 8) {
        int s[8]; float c[8]; float2 hs[8];
#pragma unroll
        for (int j = 0; j < 8; ++j) { s[j] = col[e + j]; c[j] = coefv[e + j]; }
#pragma unroll
        for (int j = 0; j < 8; ++j) hs[j] = H2[(size_t)s[j] * D2 + lane];
#pragma unroll
        for (int j = 0; j < 8; ++j) {
            ax = fmaf(hs[j].x, c[j], ax);
            ay = fmaf(hs[j].y, c[j], ay);
        }
    }
    for (; e < e1; ++e) {
        int s = col[e];
        float c = coefv[e];
        float2 hs = H2[(size_t)s * D2 + lane];
        ax = fmaf(hs.x, c, ax);
        ay = fmaf(hs.y, c, ay);
    }
    float2 bv = ((const float2*)bias)[lane];
    float ox = ax + bv.x;
    float oy = ay + bv.y;
    ox = ox > 0.f ? ox : 0.f;
    oy = oy > 0.f ? oy : 0.f;
    ((float2*)Y)[(size_t)v * D2 + lane] = make_float2(ox, oy);
}

// ---------------- launch ----------------

extern "C" void kernel_launch(void* const* d_in, const int* in_sizes, int n_in,
                              void* d_out, int out_size, void* d_ws, size_t ws_size,
                              hipStream_t stream) {
    const float* x = (const float*)d_in[0];
    const int* ei = (const int*)d_in[1];
    const float* W = (const float*)d_in[2];
    const float* b = (const float*)d_in[3];
    float* out = (float*)d_out;

    const int N = in_sizes[0] / D;       // 50000
    const int E = in_sizes[1] / 2;       // 800000

    const int* src = ei;
    const int* dst = ei + E;

    // Workspace layout (4-byte element offsets). degInt & cursor adjacent so
    // one memset zeroes both.
    int* wsi = (int*)d_ws;
    float* wsf = (float*)d_ws;
    const size_t o_deg    = 0;               // N ints (zeroed)
    const size_t o_cursor = o_deg + 50000;   // N ints (zeroed)
    const size_t o_dinv   = o_cursor + 50000;// N floats
    const size_t o_rp     = o_dinv + 50000;  // N+1 ints (pad to 50016)
    const size_t o_col    = o_rp + 50016;    // E ints
    const size_t o_coef   = o_col + 800000;  // E floats
    const size_t o_h      = o_coef + 800000; // N*D floats
    const size_t o_y1     = o_h + 6400000;   // N*D floats

    int* degInt  = wsi + o_deg;
    int* cursor  = wsi + o_cursor;
    float* dinv  = wsf + o_dinv;
    int* row_ptr = wsi + o_rp;
    int* col     = wsi + o_col;
    float* coefv = wsf + o_coef;
    float* h     = wsf + o_h;
    float* y1    = wsf + o_y1;

    const int nb_e = (E + 255) / 256;  // 3125

    hipMemsetAsync(degInt, 0, (size_t)2 * 50000 * sizeof(int), stream);  // deg + cursor
    count_kernel<<<nb_e, 256, 0, stream>>>(dst, degInt, E);
    scan_kernel<<<1, 1024, 0, stream>>>(degInt, row_ptr, dinv, N);
    fill_kernel<<<nb_e, 256, 0, stream>>>(src, dst, row_ptr, cursor, dinv, col, coefv, E);

    const int nb_gemm = (N + 63) / 64;   // 782
    const int nb_agg  = (N + 3) / 4;     // 12500

    gemm_kernel<<<nb_gemm, 256, 0, stream>>>(x, W, h, N);
    agg_kernel<<<nb_agg, 256, 0, stream>>>(h, col, coefv, row_ptr, dinv, b, y1, N);
    gemm_kernel<<<nb_gemm, 256, 0, stream>>>(y1, W + D * D, h, N);
    agg_kernel<<<nb_agg, 256, 0, stream>>>(h, col, coefv, row_ptr, dinv, b + D, out, N);
}

// Round 3
// 359.711 us; speedup vs baseline: 1.3309x; 1.2870x over previous
//
#include <hip/hip_runtime.h>

// StaticGNN: 2-layer GCN. N=50000, E=800000, D=128, fp32.
// out = relu( D^{-1/2}(A+I)D^{-1/2} (X W_l) + b_l ), stacked twice.

#define D 128
#define D4 32   // D/4 float4s per row
#define D2 64   // D/2 float2s per row
#define SCAN_B 256

// ---------------- setup kernels ----------------

// degInt starts zeroed (memset); counts in-edges only; deg = count + 1 (self-loop).
__global__ void count_kernel(const int* __restrict__ dst, int* degInt, int e) {
    int i = blockIdx.x * blockDim.x + threadIdx.x;
    if (i < e) atomicAdd(&degInt[dst[i]], 1);
}

// Phase A: per-block sums of degInt (256 elements per block).
__global__ __launch_bounds__(SCAN_B) void scanA_kernel(const int* __restrict__ degInt,
                                                       int* __restrict__ partial, int n) {
    __shared__ int red[SCAN_B / 64];
    int tid = threadIdx.x;
    int i = blockIdx.x * SCAN_B + tid;
    int c = (i < n) ? degInt[i] : 0;
    // wave reduce
    int s = c;
    for (int off = 32; off > 0; off >>= 1) s += __shfl_down(s, off, 64);
    if ((tid & 63) == 0) red[tid >> 6] = s;
    __syncthreads();
    if (tid == 0) {
        int t = 0;
#pragma unroll
        for (int w = 0; w < SCAN_B / 64; ++w) t += red[w];
        partial[blockIdx.x] = t;
    }
}

// Phase B: single block scans nb partials -> blockoff (exclusive), blockoff[nb]=total.
__global__ __launch_bounds__(256) void scanB_kernel(const int* __restrict__ partial,
                                                    int* __restrict__ blockoff, int nb) {
    __shared__ int sc[256];
    int tid = threadIdx.x;
    int c = (tid < nb) ? partial[tid] : 0;
    sc[tid] = c;
    __syncthreads();
    for (int off = 1; off < 256; off <<= 1) {
        int v = (tid >= off) ? sc[tid - off] : 0;
        __syncthreads();
        sc[tid] += v;
        __syncthreads();
    }
    if (tid <= nb) blockoff[tid] = (tid == 0) ? 0 : sc[tid - 1];
    if (tid == 255 && nb > 255) { /* unreachable for nb<=256 */ }
}

// Phase C: per-block exclusive scan + global base -> row_ptr; fused dinv.
__global__ __launch_bounds__(SCAN_B) void scanC_kernel(const int* __restrict__ degInt,
                                                       const int* __restrict__ blockoff,
                                                       int* __restrict__ row_ptr,
                                                       float* __restrict__ dinv,
                                                       int n, int nb) {
    __shared__ int sc[SCAN_B];
    int tid = threadIdx.x;
    int i = blockIdx.x * SCAN_B + tid;
    int c = (i < n) ? degInt[i] : 0;
    sc[tid] = c;
    __syncthreads();
    for (int off = 1; off < SCAN_B; off <<= 1) {
        int v = (tid >= off) ? sc[tid - off] : 0;
        __syncthreads();
        sc[tid] += v;
        __syncthreads();
    }
    if (i < n) {
        int excl = sc[tid] - c;
        row_ptr[i] = blockoff[blockIdx.x] + excl;
        dinv[i] = rsqrtf((float)(c + 1));
    }
    if (blockIdx.x == 0 && tid == 0) row_ptr[n] = blockoff[nb];  // total = E
}

__global__ void fill_kernel(const int* __restrict__ src, const int* __restrict__ dst,
                            const int* __restrict__ row_ptr, int* cursor,
                            const float* __restrict__ dinv,
                            int* __restrict__ col, float* __restrict__ coefv, int e) {
    int i = blockIdx.x * blockDim.x + threadIdx.x;
    if (i < e) {
        int d = dst[i];
        int s = src[i];
        int pos = row_ptr[d] + atomicAdd(&cursor[d], 1);
        col[pos] = s;
        coefv[pos] = dinv[s] * dinv[d];
    }
}

// ---------------- GEMM: H[n x 128] = X[n x 128] @ W[128 x 128] ----------------

__global__ __launch_bounds__(256) void gemm_kernel(const float* __restrict__ X,
                                                   const float* __restrict__ W,
                                                   float* __restrict__ H, int n) {
    __shared__ float xs[64 * 128];  // 32 KB
    const int row0 = blockIdx.x * 64;
    const int tid = threadIdx.x;

    const float4* X4 = (const float4*)X;
    float4* xs4 = (float4*)xs;
#pragma unroll
    for (int q = 0; q < 8; ++q) {
        int idx = tid + q * 256;          // 0..2047
        int r = idx >> 5;                 // tile row
        int c4 = idx & 31;                // float4 col
        int gr = row0 + r; if (gr >= n) gr = n - 1;
        xs4[idx] = X4[gr * D4 + c4];
    }
    __syncthreads();

    const int tx = tid & 31;
    const int ty = tid >> 5;
    float4 acc[8];
#pragma unroll
    for (int i = 0; i < 8; ++i) acc[i] = make_float4(0.f, 0.f, 0.f, 0.f);

    const float4* W4 = (const float4*)W;
    for (int k4 = 0; k4 < 32; ++k4) {
        float4 a[8];
#pragma unroll
        for (int i = 0; i < 8; ++i) a[i] = xs4[(ty * 8 + i) * 32 + k4];
#pragma unroll
        for (int kk = 0; kk < 4; ++kk) {
            float4 w = W4[(k4 * 4 + kk) * 32 + tx];
#pragma unroll
            for (int i = 0; i < 8; ++i) {
                float av = (kk == 0) ? a[i].x : (kk == 1) ? a[i].y : (kk == 2) ? a[i].z : a[i].w;
                acc[i].x = fmaf(av, w.x, acc[i].x);
                acc[i].y = fmaf(av, w.y, acc[i].y);
                acc[i].z = fmaf(av, w.z, acc[i].z);
                acc[i].w = fmaf(av, w.w, acc[i].w);
            }
        }
    }

    float4* H4 = (float4*)H;
#pragma unroll
    for (int i = 0; i < 8; ++i) {
        int r = row0 + ty * 8 + i;
        if (r < n) H4[r * D4 + tx] = acc[i];
    }
}

// ---------------- Aggregation ----------------
// Y[v] = relu( sum_{e->v} coef*H[src] + dinv[v]^2 * H[v] + b )
// One wave per node, lane owns a float2; edge loop unrolled x8 for MLP.

__global__ __launch_bounds__(256) void agg_kernel(const float* __restrict__ H,
                                                  const int* __restrict__ col,
                                                  const float* __restrict__ coefv,
                                                  const int* __restrict__ row_ptr,
                                                  const float* __restrict__ dinv,
                                                  const float* __restrict__ bias,
                                                  float* __restrict__ Y, int n) {
    int wave = threadIdx.x >> 6;
    int lane = threadIdx.x & 63;
    int v = blockIdx.x * 4 + wave;
    if (v >= n) return;

    const float2* H2 = (const float2*)H;
    float di = dinv[v];
    float selfc = di * di;
    float2 hv = H2[(size_t)v * D2 + lane];
    float ax = hv.x * selfc;
    float ay = hv.y * selfc;

    int e0 = row_ptr[v];
    int e1 = row_ptr[v + 1];
    int e = e0;
    for (; e + 8 <= e1; e += 8) {
        int s[8]; float c[8]; float2 hs[8];
#pragma unroll
        for (int j = 0; j < 8; ++j) { s[j] = col[e + j]; c[j] = coefv[e + j]; }
#pragma unroll
        for (int j = 0; j < 8; ++j) hs[j] = H2[(size_t)s[j] * D2 + lane];
#pragma unroll
        for (int j = 0; j < 8; ++j) {
            ax = fmaf(hs[j].x, c[j], ax);
            ay = fmaf(hs[j].y, c[j], ay);
        }
    }
    for (; e < e1; ++e) {
        int s = col[e];
        float c = coefv[e];
        float2 hs = H2[(size_t)s * D2 + lane];
        ax = fmaf(hs.x, c, ax);
        ay = fmaf(hs.y, c, ay);
    }
    float2 bv = ((const float2*)bias)[lane];
    float ox = ax + bv.x;
    float oy = ay + bv.y;
    ox = ox > 0.f ? ox : 0.f;
    oy = oy > 0.f ? oy : 0.f;
    ((float2*)Y)[(size_t)v * D2 + lane] = make_float2(ox, oy);
}

// ---------------- launch ----------------

extern "C" void kernel_launch(void* const* d_in, const int* in_sizes, int n_in,
                              void* d_out, int out_size, void* d_ws, size_t ws_size,
                              hipStream_t stream) {
    const float* x = (const float*)d_in[0];
    const int* ei = (const int*)d_in[1];
    const float* W = (const float*)d_in[2];
    const float* b = (const float*)d_in[3];
    float* out = (float*)d_out;

    const int N = in_sizes[0] / D;       // 50000
    const int E = in_sizes[1] / 2;       // 800000

    const int* src = ei;
    const int* dst = ei + E;

    // Workspace layout (4-byte element offsets). degInt & cursor adjacent so
    // one memset zeroes both.
    int* wsi = (int*)d_ws;
    float* wsf = (float*)d_ws;
    const size_t o_deg    = 0;               // N ints (zeroed)
    const size_t o_cursor = o_deg + 50000;   // N ints (zeroed)
    const size_t o_dinv   = o_cursor + 50000;// N floats
    const size_t o_rp     = o_dinv + 50000;  // N+1 ints (pad to 50016)
    const size_t o_part   = o_rp + 50016;    // 256 ints (block partials)
    const size_t o_boff   = o_part + 256;    // 256 ints (block offsets)
    const size_t o_col    = o_boff + 256;    // E ints
    const size_t o_coef   = o_col + 800000;  // E floats
    const size_t o_h      = o_coef + 800000; // N*D floats
    const size_t o_y1     = o_h + 6400000;   // N*D floats

    int* degInt  = wsi + o_deg;
    int* cursor  = wsi + o_cursor;
    float* dinv  = wsf + o_dinv;
    int* row_ptr = wsi + o_rp;
    int* partial = wsi + o_part;
    int* blockoff= wsi + o_boff;
    int* col     = wsi + o_col;
    float* coefv = wsf + o_coef;
    float* h     = wsf + o_h;
    float* y1    = wsf + o_y1;

    const int nb_e = (E + 255) / 256;          // 3125
    const int nb_s = (N + SCAN_B - 1) / SCAN_B; // 196

    hipMemsetAsync(degInt, 0, (size_t)2 * 50000 * sizeof(int), stream);  // deg + cursor
    count_kernel<<<nb_e, 256, 0, stream>>>(dst, degInt, E);
    scanA_kernel<<<nb_s, SCAN_B, 0, stream>>>(degInt, partial, N);
    scanB_kernel<<<1, 256, 0, stream>>>(partial, blockoff, nb_s);
    scanC_kernel<<<nb_s, SCAN_B, 0, stream>>>(degInt, blockoff, row_ptr, dinv, N, nb_s);
    fill_kernel<<<nb_e, 256, 0, stream>>>(src, dst, row_ptr, cursor, dinv, col, coefv, E);

    const int nb_gemm = (N + 63) / 64;   // 782
    const int nb_agg  = (N + 3) / 4;     // 12500

    gemm_kernel<<<nb_gemm, 256, 0, stream>>>(x, W, h, N);
    agg_kernel<<<nb_agg, 256, 0, stream>>>(h, col, coefv, row_ptr, dinv, b, y1, N);
    gemm_kernel<<<nb_gemm, 256, 0, stream>>>(y1, W + D * D, h, N);
    agg_kernel<<<nb_agg, 256, 0, stream>>>(h, col, coefv, row_ptr, dinv, b + D, out, N);
}